// Round 3
// baseline (284.257 us; speedup 1.0000x reference)
//
#include <hip/hip_runtime.h>
#include <math.h>

#define NB 8
#define NS 1024
#define NV 32000
#define NROWS (NB * NS)          // 8192
#define RPB 4                    // rows (waves) per 256-thread block
#define NBLK (NROWS / RPB)       // 2048
#define N4 (NV / 4)              // 8000 float4 per row
#define ITERS (N4 / 64)          // 125 iterations per wave, exact
#define FXSCALE 16777216.0f      // 2^24 fixed-point scale

// workspace layout (d_ws): [24 x u64 sums][24 x u32 counts][1 x u32 counter]
// = 192 + 96 + 4 bytes; we memset the first 512 B each call.

__global__ __launch_bounds__(256)
void fused_loss_kernel(const float* __restrict__ logits,
                       const int* __restrict__ inp,
                       const int* __restrict__ tgt,
                       float* __restrict__ out,
                       unsigned long long* __restrict__ sums,
                       unsigned int* __restrict__ cnts,
                       unsigned int* __restrict__ ctr) {
    const int wave = threadIdx.x >> 6;
    const int lane = threadIdx.x & 63;
    const int row = blockIdx.x * RPB + wave;      // wave-uniform
    const float* rp = logits + (size_t)row * NV;
    const float4* rp4 = (const float4*)rp;

    // target logit: wave-uniform address, single cache line, issued early so
    // the miss overlaps the stream below
    const float lt = rp[tgt[row]];

    // ---- uncentered exp-sum: no trans op in the serial dep chain ----
    float s0 = 0.f, s1 = 0.f;
    int i = lane;
    #pragma unroll 5
    for (int it = 0; it < ITERS; ++it, i += 64) {
        float4 x = rp4[i];
        s0 += __expf(x.x) + __expf(x.y);
        s1 += __expf(x.z) + __expf(x.w);
    }
    float s = s0 + s1;
    #pragma unroll
    for (int off = 1; off < 64; off <<= 1)
        s += __shfl_xor(s, off, 64);              // all lanes hold full sum

    float nllv;
    if (s > 1.0e-30f && s < 3.0e38f) {            // fast path (wave-uniform)
        nllv = __logf(s) - lt;
    } else {
        // wave-uniform fallback: centered two-pass (row is L2-warm)
        float m = -INFINITY;
        int j = lane;
        for (int it = 0; it < ITERS; ++it, j += 64) {
            float4 x = rp4[j];
            m = fmaxf(m, fmaxf(fmaxf(x.x, x.y), fmaxf(x.z, x.w)));
        }
        #pragma unroll
        for (int off = 1; off < 64; off <<= 1)
            m = fmaxf(m, __shfl_xor(m, off, 64));
        float c0 = 0.f, c1 = 0.f;
        j = lane;
        for (int it = 0; it < ITERS; ++it, j += 64) {
            float4 x = rp4[j];
            c0 += __expf(x.x - m) + __expf(x.y - m);
            c1 += __expf(x.z - m) + __expf(x.w - m);
        }
        float c = c0 + c1;
        #pragma unroll
        for (int off = 1; off < 64; off <<= 1)
            c += __shfl_xor(c, off, 64);
        nllv = m + __logf(c) - lt;
    }

    // ---- per-row category accumulation (deterministic fixed-point) ----
    if (lane == 0) {
        int tok = inp[row];
        int k = (tok == 4) ? 1 : (((unsigned)tok < 4u) ? 2 : 0); // 0=reg,1=msk,2=spc
        int b = row >> 10;                                       // NS == 1024
        long long q = (long long)(nllv * FXSCALE);
        atomicAdd(&sums[b * 3 + k], (unsigned long long)q);
        atomicAdd(&cnts[b * 3 + k], 1u);
    }

    // ---- last block finalizes ----
    __syncthreads();                 // drains this block's atomics (vmcnt(0))
    if (threadIdx.x == 0) {
        __threadfence();
        unsigned int old = atomicAdd(ctr, 1u);
        if (old == (unsigned int)(gridDim.x - 1)) {
            // all blocks' atomics are complete & coherent; read via atomic RMW
            const float W[3] = {1.0f, 1.0f, 0.01f};
            float loss_acc = 0.f;
            float sum_m[3] = {0.f, 0.f, 0.f};
            float sum_p[3] = {0.f, 0.f, 0.f};
            for (int bb = 0; bb < NB; ++bb) {
                float num = 0.f, tw = 0.f;
                #pragma unroll
                for (int k = 0; k < 3; ++k) {
                    long long sll =
                        (long long)atomicAdd(&sums[bb * 3 + k], 0ull);
                    unsigned int cn = atomicAdd(&cnts[bb * 3 + k], 0u);
                    float sv = (float)((double)sll / 16777216.0);
                    float p = (cn > 0u) ? 1.f : 0.f;
                    float mean = (cn > 0u) ? (sv / (float)cn) : 0.f;
                    num += mean * W[k] * p;
                    tw  += p * W[k];
                    sum_m[k] += mean;
                    sum_p[k] += p;
                }
                loss_acc += num / tw;
            }
            out[0] = loss_acc / (float)NB;
            #pragma unroll
            for (int k = 0; k < 3; ++k)
                out[1 + k] = (sum_p[k] > 0.f)
                                 ? (sum_m[k] / fmaxf(sum_p[k], 1.f))
                                 : 0.f;
        }
    }
}

// ---------------------------------------------------------------------------
extern "C" void kernel_launch(void* const* d_in, const int* in_sizes, int n_in,
                              void* d_out, int out_size, void* d_ws, size_t ws_size,
                              hipStream_t stream) {
    const float* logits = (const float*)d_in[0];   // [B,S,V] f32
    const int*   inp    = (const int*)d_in[1];     // [B,S] i32
    const int*   tgt    = (const int*)d_in[2];     // [B,S] i32
    float* out = (float*)d_out;                    // 4 f32

    unsigned long long* sums = (unsigned long long*)d_ws;        // 24 x u64
    unsigned int* cnts = (unsigned int*)(sums + NB * 3);         // 24 x u32
    unsigned int* ctr  = cnts + NB * 3;                          // 1 x u32

    hipMemsetAsync(d_ws, 0, 512, stream);          // graph-capturable node
    fused_loss_kernel<<<NBLK, 256, 0, stream>>>(logits, inp, tgt,
                                                out, sums, cnts, ctr);
}